// Round 1
// baseline (299.703 us; speedup 1.0000x reference)
//
#include <hip/hip_runtime.h>
#include <hip/hip_bf16.h>
#include <math.h>

// Problem constants (fixed by the reference's weight shapes):
#define DM     256   // d_model
#define NHEAD  8
#define HDIM   32
#define QPAD   112   // padded query rows per (b,h): 7 waves x 16 rows
#define NCHUNK 8     // L-chunks per (b,h) for flash parallelism
#define BM     64    // kv_gemm M-tile (tokens)
#define BN     256   // kv_gemm N-tile (output cols): block 0 = K, block 1 = V
#define BK     32    // kv_gemm K-step

typedef __attribute__((ext_vector_type(8))) short bf16x8;  // 8 bf16 (4 VGPRs)
typedef __attribute__((ext_vector_type(4))) short bf16x4;  // 8B packed store
typedef __attribute__((ext_vector_type(4))) float f32x4;   // 4 fp32 acc

__device__ __forceinline__ short f2bf(float f) {
  union { float f; unsigned u; } x; x.f = f;
  unsigned u = (x.u + 0x7fffu + ((x.u >> 16) & 1u)) >> 16;
  return (short)u;
}
__device__ __forceinline__ float bf2f(short s) {
  union { unsigned u; float f; } x; x.u = ((unsigned)(unsigned short)s) << 16;
  return x.f;
}
__device__ __forceinline__ bf16x8 bzero8() {
  bf16x8 v;
#pragma unroll
  for (int j = 0; j < 8; j++) v[j] = (short)0;
  return v;
}
__device__ __forceinline__ void gl2lds16(const void* g, void* l) {
  __builtin_amdgcn_global_load_lds(
      (const __attribute__((address_space(1))) unsigned*)g,
      (__attribute__((address_space(3))) unsigned*)l, 16, 0, 0);
}
__device__ __forceinline__ bf16x8 cvt8(const float* p) {
  float4 x0 = *(const float4*)p, x1 = *(const float4*)(p + 4);
  bf16x8 v;
  v[0] = f2bf(x0.x); v[1] = f2bf(x0.y); v[2] = f2bf(x0.z); v[3] = f2bf(x0.w);
  v[4] = f2bf(x1.x); v[5] = f2bf(x1.y); v[6] = f2bf(x1.z); v[7] = f2bf(x1.w);
  return v;
}
__device__ __forceinline__ bf16x8 pack8(float4 x0, float4 x1) {
  bf16x8 v;
  v[0] = f2bf(x0.x); v[1] = f2bf(x0.y); v[2] = f2bf(x0.z); v[3] = f2bf(x0.w);
  v[4] = f2bf(x1.x); v[5] = f2bf(x1.y); v[6] = f2bf(x1.z); v[7] = f2bf(x1.w);
  return v;
}

// ---------------------------------------------------------------------------
// Kernel 0: weight convert.  Wkv[n][k] bf16; n<256 -> Wk row n, else Wv.
// ---------------------------------------------------------------------------
__global__ __launch_bounds__(256) void wconv_kernel(
    const float* __restrict__ Wk, const float* __restrict__ Wv,
    short* __restrict__ Wkv) {
  int idx = blockIdx.x * 256 + threadIdx.x;
  int e0 = idx * 8;
  const float* p = (e0 < DM * DM) ? (Wk + e0) : (Wv + (e0 - DM * DM));
  *(bf16x8*)(Wkv + e0) = cvt8(p);
}

// ---------------------------------------------------------------------------
// Kernel 1: Q projection.  q = (query @ Wq^T + bq) * scale, bf16,
// layout Qw[b][h][row(QPAD)][hd], rows >= NQ zero-filled.
// ---------------------------------------------------------------------------
__global__ __launch_bounds__(256) void q_proj_kernel(
    const float* __restrict__ query, const float* __restrict__ Wq,
    const float* __restrict__ bq, short* __restrict__ Qw, int Bn, int NQ) {
  int b  = blockIdx.x / (QPAD / 8);
  int r0 = (blockIdx.x % (QPAD / 8)) * 8;
  __shared__ __align__(16) float ql[8 * DM];
  int tid = threadIdx.x;
  for (int i = tid; i < 8 * DM; i += 256) {
    int r = r0 + (i >> 8);
    ql[i] = (r < NQ) ? query[((size_t)b * NQ + r) * DM + (i & 255)] : 0.f;
  }
  __syncthreads();
  int d = tid;
  float bias = bq[d];
  float acc[8];
#pragma unroll
  for (int qi = 0; qi < 8; qi++) acc[qi] = bias;
  const float* wrow = Wq + (size_t)d * DM;
  for (int k = 0; k < DM; k += 4) {
    float4 w = *(const float4*)(wrow + k);
#pragma unroll
    for (int qi = 0; qi < 8; qi++) {
      float4 x = *(const float4*)&ql[qi * DM + k];
      acc[qi] += x.x * w.x + x.y * w.y + x.z * w.z + x.w * w.w;
    }
  }
  const float scale = 0.17677669529663687f;  // 1/sqrt(32)
  int h = d >> 5, hd = d & 31;
#pragma unroll
  for (int qi = 0; qi < 8; qi++) {
    int r = r0 + qi;
    float v = (r < NQ) ? acc[qi] * scale : 0.f;
    Qw[(((size_t)b * NHEAD + h) * QPAD + r) * HDIM + hd] = f2bf(v);
  }
}

// ---------------------------------------------------------------------------
// Kernel 2: KV projection GEMM, 64x256 tile, 4 waves (1x4 over N), 2-phase
// double-buffered pipeline (one barrier per K-step).
//   - ntile 0 computes all 256 K-cols, ntile 1 all 256 V-cols.
//   - Block swizzle: mtile=(bid>>4)*8+(bid&7), ntile=(bid>>3)&1, so the K and
//     V blocks of one mtile share bid%8 (same XCD) and are 8 IDs apart
//     (same dispatch round) -> second src read is an L2 hit.
//   - Per K-step: issue next A-loads (reg) + next B global_load_lds into
//     buf^1, ds_read+MFMA from buf, cvt+ds_write A into buf^1, one barrier.
// B: bf16 weights via global_load_lds with XOR k-slot swizzle
// (slot' = quad ^ ((col>>1)&3)) -> 2-way-free reads. K tiles use SWAPPED
// mfma operands (C^T: reg=hd, lane=token); V tiles normal orientation.
// ---------------------------------------------------------------------------
__global__ __launch_bounds__(256) void kv_gemm_kernel(
    const float* __restrict__ src, const short* __restrict__ Wkv,
    const float* __restrict__ bk, const float* __restrict__ bv,
    const int* __restrict__ offs, short* __restrict__ Kw,
    short* __restrict__ Vw, int T, int Bn, int Mtiles) {
  int bid = blockIdx.x;
  int mtile = (bid >> 4) * 8 + (bid & 7);
  int ntile = (bid >> 3) & 1;
  if (mtile >= Mtiles) return;
  int t0 = mtile * BM;
  int n0 = ntile * BN;           // 0 => K cols, 256 => V cols
  bool isK = (ntile == 0);
  const float* bias = isK ? bk : bv;

  int tid = threadIdx.x;
  int wave = tid >> 6, lane = tid & 63;
  int l15 = lane & 15, quad = lane >> 4;

  __shared__ __align__(16) short As[2][BM][BK + 8];  // padded (80B stride)
  __shared__ __align__(16) short Bs[2][BN * BK];     // swizzled k-slots

  f32x4 acc[4][4];
#pragma unroll
  for (int i = 0; i < 4; i++)
#pragma unroll
    for (int j = 0; j < 4; j++) acc[i][j] = (f32x4){0.f, 0.f, 0.f, 0.f};

  // Per-thread A staging: row = tid>>2 (0..63), 8-float chunk = tid&3.
  int arow = tid >> 2, ach = tid & 3;
  int atok = t0 + arow;
  if (atok >= T) atok = T - 1;
  const float* asrc = src + (size_t)atok * DM + ach * 8;

#define STAGE_B(buf, kk)                                                   \
  {                                                                        \
    int cloc = lane >> 2;                                                  \
    for (int j = 0; j < 4; j++) {                                          \
      int cb = wave * 64 + j * 16;        /* wave-uniform LDS base col */  \
      int c = cb + cloc;                  /* tile col this lane fetches */ \
      int slot = (lane & 3) ^ ((c >> 1) & 3);                              \
      const short* g = Wkv + (size_t)(n0 + c) * DM + (kk) + slot * 8;      \
      gl2lds16(g, &Bs[buf][cb * BK]);                                      \
    }                                                                      \
  }

  // ---- prologue: stage K-step 0 into buffer 0 ----
  {
    float4 a0 = *(const float4*)asrc;
    float4 a1 = *(const float4*)(asrc + 4);
    STAGE_B(0, 0);
    *(bf16x8*)&As[0][arow][ach * 8] = pack8(a0, a1);
  }
  __syncthreads();

  for (int ki = 0; ki < DM / BK; ki++) {
    int cur = ki & 1;
    bool more = (ki + 1 < DM / BK);
    float4 na0, na1;
    if (more) {
      const float* ap = asrc + (ki + 1) * BK;
      na0 = *(const float4*)ap;         // issue next A loads early
      na1 = *(const float4*)(ap + 4);
      STAGE_B(cur ^ 1, (ki + 1) * BK);  // issue next B gl2lds into buf^1
    }
    // ---- fragments + MFMA from buf[cur] ----
    bf16x8 af[4], bf_[4];
#pragma unroll
    for (int mt = 0; mt < 4; mt++)
      af[mt] = *(const bf16x8*)&As[cur][mt * 16 + l15][quad * 8];
#pragma unroll
    for (int nt = 0; nt < 4; nt++) {
      int c = wave * 64 + nt * 16 + l15;
      int slot = quad ^ ((c >> 1) & 3);
      bf_[nt] = *(const bf16x8*)&Bs[cur][c * BK + slot * 8];
    }
    if (isK) {
#pragma unroll
      for (int mt = 0; mt < 4; mt++)
#pragma unroll
        for (int nt = 0; nt < 4; nt++)
          acc[mt][nt] = __builtin_amdgcn_mfma_f32_16x16x32_bf16(
              bf_[nt], af[mt], acc[mt][nt], 0, 0, 0);  // C^T
    } else {
#pragma unroll
      for (int mt = 0; mt < 4; mt++)
#pragma unroll
        for (int nt = 0; nt < 4; nt++)
          acc[mt][nt] = __builtin_amdgcn_mfma_f32_16x16x32_bf16(
              af[mt], bf_[nt], acc[mt][nt], 0, 0, 0);
    }
    if (more)  // cvt + write next A tile into buf^1 (loads landed by now)
      *(bf16x8*)&As[cur ^ 1][arow][ach * 8] = pack8(na0, na1);
    __syncthreads();  // drains gl2lds (vmcnt) + lds writes (lgkm)
  }
#undef STAGE_B

  if (isK) {
    // C^T: lane l15 = token (within 16), reg r = hd offset quad*4+r.
    float bk4[4][4];
    int hK[4], hdK[4];
#pragma unroll
    for (int nt = 0; nt < 4; nt++) {
      int nbq = wave * 64 + nt * 16 + quad * 4;
      float4 b4 = *(const float4*)(bias + nbq);
      bk4[nt][0] = b4.x; bk4[nt][1] = b4.y; bk4[nt][2] = b4.z; bk4[nt][3] = b4.w;
      hK[nt] = nbq >> 5;
      hdK[nt] = nbq & 31;
    }
    int bcur = 0;
#pragma unroll
    for (int mt = 0; mt < 4; mt++) {
      int tok = t0 + mt * 16 + l15;
      if (tok >= T) continue;
      while (bcur + 1 < Bn && offs[bcur + 1] <= tok) bcur++;
      int off = offs[bcur], len = offs[bcur + 1] - off;
      int l = tok - off;
      size_t bb = (size_t)off * DM;
#pragma unroll
      for (int nt = 0; nt < 4; nt++) {
        bf16x4 p;
#pragma unroll
        for (int r = 0; r < 4; r++) p[r] = f2bf(acc[mt][nt][r] + bk4[nt][r]);
        *(bf16x4*)&Kw[bb + (size_t)hK[nt] * len * HDIM + (size_t)l * HDIM +
                      hdK[nt]] = p;
      }
    }
  } else {
    // Normal C: lane l15 = hd (within 16), reg r = token offset quad*4+r.
    float bV[4];
    int hV[4], hdV[4];
#pragma unroll
    for (int nt = 0; nt < 4; nt++) {
      int nb = wave * 64 + nt * 16 + l15;
      bV[nt] = bias[nb];
      hV[nt] = nb >> 5;
      hdV[nt] = nb & 31;
    }
    int bcur = 0;
#pragma unroll
    for (int mt = 0; mt < 4; mt++) {
      int tb = t0 + mt * 16 + quad * 4;
      if (tb >= T) continue;
      while (bcur + 1 < Bn && offs[bcur + 1] <= tb) bcur++;
      int off = offs[bcur], len = offs[bcur + 1] - off;
      size_t bb = (size_t)off * DM;
      bool span = (tb + 3 < offs[bcur + 1]) && (tb + 3 < T);
      if (span) {
        int l = tb - off;
#pragma unroll
        for (int nt = 0; nt < 4; nt++) {
          size_t idx =
              bb + (size_t)hV[nt] * len * HDIM + (size_t)hdV[nt] * len + l;
          bf16x4 p;
#pragma unroll
          for (int r = 0; r < 4; r++) p[r] = f2bf(acc[mt][nt][r] + bV[nt]);
          if ((idx & 3) == 0) {
            *(bf16x4*)&Vw[idx] = p;
          } else {
#pragma unroll
            for (int r = 0; r < 4; r++) Vw[idx + r] = p[r];
          }
        }
      } else {
        int bc2 = bcur;
#pragma unroll
        for (int r = 0; r < 4; r++) {
          int tok = tb + r;
          if (tok >= T) continue;
          while (bc2 + 1 < Bn && offs[bc2 + 1] <= tok) bc2++;
          int off2 = offs[bc2], len2 = offs[bc2 + 1] - off2;
          int l = tok - off2;
          size_t bb2 = (size_t)off2 * DM;
#pragma unroll
          for (int nt = 0; nt < 4; nt++)
            Vw[bb2 + (size_t)hV[nt] * len2 * HDIM + (size_t)hdV[nt] * len2 +
               l] = f2bf(acc[mt][nt][r] + bV[nt]);
        }
      }
    }
  }
}

// ---------------------------------------------------------------------------
// Kernel 3: flash attention per (b, h, chunk). 7 waves x 16 query rows.
// Writes unnormalized O (QPAD x 32, bf16) + per-row (m, l) fp32.
// ---------------------------------------------------------------------------
__global__ __launch_bounds__(448) void attn_kernel(
    const short* __restrict__ Qw, const short* __restrict__ Kw,
    const short* __restrict__ Vw, const int* __restrict__ offs,
    short* __restrict__ Ops, float* __restrict__ Ml, int Bn) {
  int c  = blockIdx.x % NCHUNK;
  int bh = blockIdx.x / NCHUNK;
  int h = bh % NHEAD, b = bh / NHEAD;
  int wave = threadIdx.x >> 6, lane = threadIdx.x & 63;
  int l15 = lane & 15, quad = lane >> 4;

  int off = offs[b], len = offs[b + 1] - off;
  int cl = ((len + NCHUNK * 32 - 1) / (NCHUNK * 32)) * 32;
  int kstart = c * cl;
  int kend   = min(kstart + cl, len);

  const short* Kh = Kw + (size_t)off * DM + (size_t)h * len * HDIM;
  const short* Vh = Vw + (size_t)off * DM + (size_t)h * len * HDIM;

  int row16 = wave * 16 + l15;
  bf16x8 aq = *(const bf16x8*)(
      Qw + (((size_t)b * NHEAD + h) * QPAD + row16) * HDIM + quad * 8);

  f32x4 o[2];
#pragma unroll
  for (int j = 0; j < 2; j++) o[j] = (f32x4){0.f, 0.f, 0.f, 0.f};
  float mrun[4], lrun[4];
#pragma unroll
  for (int r = 0; r < 4; r++) { mrun[r] = -1e30f; lrun[r] = 0.f; }

  __shared__ __align__(16) short plds[7][16][40];  // wave-private P transpose

  for (int kb = kstart; kb < kend; kb += 32) {
    bool valid[2];
    bf16x8 bk_[2];
#pragma unroll
    for (int nt = 0; nt < 2; nt++) {
      int key = kb + nt * 16 + l15;
      valid[nt] = key < kend;
      bk_[nt] = valid[nt]
                    ? *(const bf16x8*)(Kh + (size_t)key * HDIM + quad * 8)
                    : bzero8();
    }
    f32x4 zero = {0.f, 0.f, 0.f, 0.f};
    f32x4 s[2];
#pragma unroll
    for (int nt = 0; nt < 2; nt++)
      s[nt] = __builtin_amdgcn_mfma_f32_16x16x32_bf16(aq, bk_[nt], zero, 0, 0, 0);
#pragma unroll
    for (int r = 0; r < 4; r++) {
      float v0 = valid[0] ? s[0][r] : -1e30f;
      float v1 = valid[1] ? s[1][r] : -1e30f;
      float t = fmaxf(v0, v1);
      t = fmaxf(t, __shfl_xor(t, 1, 16));
      t = fmaxf(t, __shfl_xor(t, 2, 16));
      t = fmaxf(t, __shfl_xor(t, 4, 16));
      t = fmaxf(t, __shfl_xor(t, 8, 16));
      float mn = fmaxf(mrun[r], t);
      float al = __expf(mrun[r] - mn);
      float p0 = valid[0] ? __expf(v0 - mn) : 0.f;
      float p1 = valid[1] ? __expf(v1 - mn) : 0.f;
      float rs = p0 + p1;
      rs += __shfl_xor(rs, 1, 16);
      rs += __shfl_xor(rs, 2, 16);
      rs += __shfl_xor(rs, 4, 16);
      rs += __shfl_xor(rs, 8, 16);
      lrun[r] = al * lrun[r] + rs;
      mrun[r] = mn;
      o[0][r] *= al;
      o[1][r] *= al;
      plds[wave][quad * 4 + r][l15]      = f2bf(p0);
      plds[wave][quad * 4 + r][16 + l15] = f2bf(p1);
    }
    bf16x8 pa = *(const bf16x8*)&plds[wave][l15][quad * 8];
    bf16x8 bv_[2];
#pragma unroll
    for (int ht = 0; ht < 2; ht++) {
      int hd = ht * 16 + l15;
      int k0 = kb + quad * 8;
      const short* p = Vh + (size_t)hd * len + k0;
      if (k0 + 7 < len) {
        bv_[ht] = *(const bf16x8*)p;
      } else {
        bf16x8 v;
#pragma unroll
        for (int j = 0; j < 8; j++) v[j] = (k0 + j < len) ? p[j] : (short)0;
        bv_[ht] = v;
      }
    }
#pragma unroll
    for (int ht = 0; ht < 2; ht++)
      o[ht] = __builtin_amdgcn_mfma_f32_16x16x32_bf16(pa, bv_[ht], o[ht], 0, 0, 0);
  }

#pragma unroll
  for (int r = 0; r < 4; r++) {
    int row = wave * 16 + quad * 4 + r;
    size_t base = (((size_t)c * Bn + b) * NHEAD + h) * QPAD + row;
#pragma unroll
    for (int ht = 0; ht < 2; ht++)
      Ops[base * HDIM + ht * 16 + l15] = f2bf(o[ht][r]);
    if (l15 == 0) {
      Ml[base * 2]     = mrun[r];
      Ml[base * 2 + 1] = lrun[r];
    }
  }
}

// ---------------------------------------------------------------------------
// Kernel 4: chunk combine + out-projection + residual.
// ---------------------------------------------------------------------------
__global__ __launch_bounds__(256) void combine_kernel(
    const short* __restrict__ Ops, const float* __restrict__ Ml,
    const float* __restrict__ query, const float* __restrict__ Wo,
    const float* __restrict__ bo, float* __restrict__ out, int Bn, int NQ) {
  int bpb = (NQ + 7) / 8;
  int b  = blockIdx.x / bpb;
  int q0 = (blockIdx.x % bpb) * 8;
  __shared__ __align__(16) float ctx[8 * DM];
  int d = threadIdx.x;
  int h = d >> 5, hd = d & 31;
#pragma unroll
  for (int qi = 0; qi < 8; qi++) {
    int q = q0 + qi;
    float val = 0.f;
    if (q < NQ) {
      float mc[NCHUNK], lc[NCHUNK], M = -1e30f;
#pragma unroll
      for (int c = 0; c < NCHUNK; c++) {
        size_t base = (((size_t)c * Bn + b) * NHEAD + h) * QPAD + q;
        mc[c] = Ml[base * 2];
        lc[c] = Ml[base * 2 + 1];
        M = fmaxf(M, mc[c]);
      }
      float L = 0.f, acc = 0.f;
#pragma unroll
      for (int c = 0; c < NCHUNK; c++) {
        size_t base = (((size_t)c * Bn + b) * NHEAD + h) * QPAD + q;
        float w = __expf(mc[c] - M);
        L += lc[c] * w;
        acc += w * bf2f(Ops[base * HDIM + hd]);
      }
      val = (L > 0.f) ? acc / L : 0.f;
    }
    ctx[qi * DM + d] = val;
  }
  __syncthreads();
  const float* wrow = Wo + (size_t)d * DM;
  float acc[8];
  float bias = bo[d];
#pragma unroll
  for (int qi = 0; qi < 8; qi++) acc[qi] = bias;
  for (int k = 0; k < DM; k += 4) {
    float4 w = *(const float4*)(wrow + k);
#pragma unroll
    for (int qi = 0; qi < 8; qi++) {
      float4 x = *(const float4*)&ctx[qi * DM + k];
      acc[qi] += x.x * w.x + x.y * w.y + x.z * w.z + x.w * w.w;
    }
  }
#pragma unroll
  for (int qi = 0; qi < 8; qi++) {
    int q = q0 + qi;
    if (q < NQ)
      out[((size_t)b * NQ + q) * DM + d] =
          acc[qi] + query[((size_t)b * NQ + q) * DM + d];
  }
}

// ---------------------------------------------------------------------------
extern "C" void kernel_launch(void* const* d_in, const int* in_sizes, int n_in,
                              void* d_out, int out_size, void* d_ws,
                              size_t ws_size, hipStream_t stream) {
  const float* src   = (const float*)d_in[0];
  const float* query = (const float*)d_in[1];
  const int*   offs  = (const int*)d_in[2];
  const float* Wq = (const float*)d_in[3];
  const float* bq = (const float*)d_in[4];
  const float* Wk = (const float*)d_in[5];
  const float* bk = (const float*)d_in[6];
  const float* Wv = (const float*)d_in[7];
  const float* bv = (const float*)d_in[8];
  const float* Wo = (const float*)d_in[9];
  const float* bo = (const float*)d_in[10];
  float* out = (float*)d_out;

  int T  = in_sizes[0] / DM;        // total tokens (65536)
  int Bn = in_sizes[2] - 1;         // batch size (16)
  int NQ = in_sizes[1] / (Bn * DM); // queries per sample (100)

  // Workspace layout (~77 MB):
  char* w = (char*)d_ws;
  size_t qsz = (size_t)Bn * NHEAD * QPAD * HDIM * 2;            // 0.92 MB
  size_t ksz = (size_t)T * DM * 2;                              // 33.5 MB
  size_t osz = (size_t)NCHUNK * Bn * NHEAD * QPAD * HDIM * 2;   // 7.3 MB (bf16)
  size_t msz = (size_t)NCHUNK * Bn * NHEAD * QPAD * 2 * 4;      // 0.92 MB
  short* Qw  = (short*)w;
  short* Kw  = (short*)(w + qsz);
  short* Vw  = (short*)(w + qsz + ksz);
  short* Ops = (short*)(w + qsz + 2 * ksz);
  float* Mlp = (float*)(w + qsz + 2 * ksz + osz);
  short* Wkv = (short*)(w + qsz + 2 * ksz + osz + msz);         // 0.26 MB

  int Mtiles = (T + BM - 1) / BM;
  int groups = (Mtiles + 7) / 8;

  wconv_kernel<<<(2 * DM * DM) / (256 * 8), 256, 0, stream>>>(Wk, Wv, Wkv);
  q_proj_kernel<<<Bn * (QPAD / 8), 256, 0, stream>>>(query, Wq, bq, Qw, Bn, NQ);
  kv_gemm_kernel<<<groups * 16, 256, 0, stream>>>(
      src, Wkv, bk, bv, offs, Kw, Vw, T, Bn, Mtiles);
  attn_kernel<<<Bn * NHEAD * NCHUNK, 448, 0, stream>>>(Qw, Kw, Vw, offs, Ops,
                                                       Mlp, Bn);
  combine_kernel<<<Bn * ((NQ + 7) / 8), 256, 0, stream>>>(Ops, Mlp, query, Wo,
                                                          bo, out, Bn, NQ);
}

// Round 2
// 273.908 us; speedup vs baseline: 1.0942x; 1.0942x over previous
//
#include <hip/hip_runtime.h>
#include <hip/hip_bf16.h>
#include <math.h>

// Problem constants (fixed by the reference's weight shapes):
#define DM     256   // d_model
#define NHEAD  8
#define HDIM   32
#define QPAD   112   // padded query rows per (b,h): 7 waves x 16 rows
#define NCHUNK 8     // L-chunks per (b,h) for flash parallelism
#define BM     64    // kv_gemm M-tile (tokens)
#define BN     256   // kv_gemm N-tile (output cols): ntile 0 = K, 1 = V
#define BK     32    // kv_gemm K-step

typedef __attribute__((ext_vector_type(8))) short bf16x8;  // 8 bf16 (4 VGPRs)
typedef __attribute__((ext_vector_type(4))) short bf16x4;  // 8B packed store
typedef __attribute__((ext_vector_type(4))) float f32x4;   // 4 fp32 acc

__device__ __forceinline__ short f2bf(float f) {
  union { float f; unsigned u; } x; x.f = f;
  unsigned u = (x.u + 0x7fffu + ((x.u >> 16) & 1u)) >> 16;
  return (short)u;
}
__device__ __forceinline__ float bf2f(short s) {
  union { unsigned u; float f; } x; x.u = ((unsigned)(unsigned short)s) << 16;
  return x.f;
}
__device__ __forceinline__ bf16x8 bzero8() {
  bf16x8 v;
#pragma unroll
  for (int j = 0; j < 8; j++) v[j] = (short)0;
  return v;
}
__device__ __forceinline__ void gl2lds16(const void* g, void* l) {
  __builtin_amdgcn_global_load_lds(
      (const __attribute__((address_space(1))) unsigned*)g,
      (__attribute__((address_space(3))) unsigned*)l, 16, 0, 0);
}
__device__ __forceinline__ bf16x8 cvt8(const float* p) {
  float4 x0 = *(const float4*)p, x1 = *(const float4*)(p + 4);
  bf16x8 v;
  v[0] = f2bf(x0.x); v[1] = f2bf(x0.y); v[2] = f2bf(x0.z); v[3] = f2bf(x0.w);
  v[4] = f2bf(x1.x); v[5] = f2bf(x1.y); v[6] = f2bf(x1.z); v[7] = f2bf(x1.w);
  return v;
}

// ---------------------------------------------------------------------------
// Kernel 0: weight convert.  Wkv[n][k] bf16; n<256 -> Wk row n, else Wv.
// ---------------------------------------------------------------------------
__global__ __launch_bounds__(256) void wconv_kernel(
    const float* __restrict__ Wk, const float* __restrict__ Wv,
    short* __restrict__ Wkv) {
  int idx = blockIdx.x * 256 + threadIdx.x;
  int e0 = idx * 8;
  const float* p = (e0 < DM * DM) ? (Wk + e0) : (Wv + (e0 - DM * DM));
  *(bf16x8*)(Wkv + e0) = cvt8(p);
}

// ---------------------------------------------------------------------------
// Kernel 1: Q projection.  q = (query @ Wq^T + bq) * scale, bf16,
// layout Qw[b][h][row(QPAD)][hd], rows >= NQ zero-filled.
// ---------------------------------------------------------------------------
__global__ __launch_bounds__(256) void q_proj_kernel(
    const float* __restrict__ query, const float* __restrict__ Wq,
    const float* __restrict__ bq, short* __restrict__ Qw, int Bn, int NQ) {
  int b  = blockIdx.x / (QPAD / 8);
  int r0 = (blockIdx.x % (QPAD / 8)) * 8;
  __shared__ __align__(16) float ql[8 * DM];
  int tid = threadIdx.x;
  for (int i = tid; i < 8 * DM; i += 256) {
    int r = r0 + (i >> 8);
    ql[i] = (r < NQ) ? query[((size_t)b * NQ + r) * DM + (i & 255)] : 0.f;
  }
  __syncthreads();
  int d = tid;
  float bias = bq[d];
  float acc[8];
#pragma unroll
  for (int qi = 0; qi < 8; qi++) acc[qi] = bias;
  const float* wrow = Wq + (size_t)d * DM;
  for (int k = 0; k < DM; k += 4) {
    float4 w = *(const float4*)(wrow + k);
#pragma unroll
    for (int qi = 0; qi < 8; qi++) {
      float4 x = *(const float4*)&ql[qi * DM + k];
      acc[qi] += x.x * w.x + x.y * w.y + x.z * w.z + x.w * w.w;
    }
  }
  const float scale = 0.17677669529663687f;  // 1/sqrt(32)
  int h = d >> 5, hd = d & 31;
#pragma unroll
  for (int qi = 0; qi < 8; qi++) {
    int r = r0 + qi;
    float v = (r < NQ) ? acc[qi] * scale : 0.f;
    Qw[(((size_t)b * NHEAD + h) * QPAD + r) * HDIM + hd] = f2bf(v);
  }
}

// ---------------------------------------------------------------------------
// Kernel 2: KV projection GEMM, 64x256 tile, 4 waves (1x4 over N).
// Single-buffer, two-barrier K-loop (round-0 structure: high occupancy,
// compiler-scheduled) + K/V-paired block swizzle (round-1 grid: the K and V
// blocks of one mtile share bid%8 (same XCD) and are 8 IDs apart (same
// dispatch round) -> the second src read is an L2 hit; FETCH ~34 MB).
// B: bf16 weights via global_load_lds with XOR k-slot swizzle
// (slot' = quad ^ ((col>>1)&3)) -> 2-way-free reads. K tiles use SWAPPED
// mfma operands (C^T: reg=hd, lane=token); V tiles normal orientation.
// ---------------------------------------------------------------------------
__global__ __launch_bounds__(256) void kv_gemm_kernel(
    const float* __restrict__ src, const short* __restrict__ Wkv,
    const float* __restrict__ bk, const float* __restrict__ bv,
    const int* __restrict__ offs, short* __restrict__ Kw,
    short* __restrict__ Vw, int T, int Bn, int Mtiles) {
  int bid = blockIdx.x;
  int mtile = (bid >> 4) * 8 + (bid & 7);
  int ntile = (bid >> 3) & 1;
  if (mtile >= Mtiles) return;
  int t0 = mtile * BM;
  int n0 = ntile * BN;           // 0 => K cols, 256 => V cols
  bool isK = (ntile == 0);
  const float* bias = isK ? bk : bv;

  int tid = threadIdx.x;
  int wave = tid >> 6, lane = tid & 63;
  int l15 = lane & 15, quad = lane >> 4;

  __shared__ __align__(16) short As[BM][BK + 8];  // padded (80B stride)
  __shared__ __align__(16) short Bs[BN * BK];     // swizzled k-slots

  f32x4 acc[4][4];
#pragma unroll
  for (int i = 0; i < 4; i++)
#pragma unroll
    for (int j = 0; j < 4; j++) acc[i][j] = (f32x4){0.f, 0.f, 0.f, 0.f};

  // Per-thread A staging: row = tid>>2 (0..63), 8-float chunk = tid&3.
  int arow = tid >> 2, ach = tid & 3;
  int atok = t0 + arow;
  if (atok >= T) atok = T - 1;
  const float* asrc = src + (size_t)atok * DM + ach * 8;

  for (int kk = 0; kk < DM; kk += BK) {
    __syncthreads();
    // ---- stage A: 64 rows x 32 k, fp32 -> bf16 ----
    *(bf16x8*)&As[arow][ach * 8] = cvt8(asrc + kk);
    // ---- stage B: 256 cols x 32 k bf16 via global_load_lds, swizzled ----
    {
      int cloc = lane >> 2;  // col within 16-col chunk
#pragma unroll
      for (int j = 0; j < 4; j++) {
        int cb = wave * 64 + j * 16;          // wave-uniform LDS base col
        int c = cb + cloc;                    // tile col this lane fetches
        int slot = (lane & 3) ^ ((c >> 1) & 3);
        const short* g = Wkv + (size_t)(n0 + c) * DM + kk + slot * 8;
        gl2lds16(g, &Bs[cb * BK]);
      }
    }
    __syncthreads();
    // ---- fragments + MFMA ----
    bf16x8 af[4], bf_[4];
#pragma unroll
    for (int mt = 0; mt < 4; mt++)
      af[mt] = *(const bf16x8*)&As[mt * 16 + l15][quad * 8];
#pragma unroll
    for (int nt = 0; nt < 4; nt++) {
      int c = wave * 64 + nt * 16 + l15;
      int slot = quad ^ ((c >> 1) & 3);
      bf_[nt] = *(const bf16x8*)&Bs[c * BK + slot * 8];
    }
    if (isK) {
#pragma unroll
      for (int mt = 0; mt < 4; mt++)
#pragma unroll
        for (int nt = 0; nt < 4; nt++)
          acc[mt][nt] = __builtin_amdgcn_mfma_f32_16x16x32_bf16(
              bf_[nt], af[mt], acc[mt][nt], 0, 0, 0);  // C^T
    } else {
#pragma unroll
      for (int mt = 0; mt < 4; mt++)
#pragma unroll
        for (int nt = 0; nt < 4; nt++)
          acc[mt][nt] = __builtin_amdgcn_mfma_f32_16x16x32_bf16(
              af[mt], bf_[nt], acc[mt][nt], 0, 0, 0);
    }
  }

  if (isK) {
    // C^T: lane l15 = token (within 16), reg r = hd offset quad*4+r.
    float bk4[4][4];
    int hK[4], hdK[4];
#pragma unroll
    for (int nt = 0; nt < 4; nt++) {
      int nbq = wave * 64 + nt * 16 + quad * 4;
      float4 b4 = *(const float4*)(bias + nbq);
      bk4[nt][0] = b4.x; bk4[nt][1] = b4.y; bk4[nt][2] = b4.z; bk4[nt][3] = b4.w;
      hK[nt] = nbq >> 5;
      hdK[nt] = nbq & 31;
    }
    int bcur = 0;
#pragma unroll
    for (int mt = 0; mt < 4; mt++) {
      int tok = t0 + mt * 16 + l15;
      if (tok >= T) continue;
      while (bcur + 1 < Bn && offs[bcur + 1] <= tok) bcur++;
      int off = offs[bcur], len = offs[bcur + 1] - off;
      int l = tok - off;
      size_t bb = (size_t)off * DM;
#pragma unroll
      for (int nt = 0; nt < 4; nt++) {
        bf16x4 p;
#pragma unroll
        for (int r = 0; r < 4; r++) p[r] = f2bf(acc[mt][nt][r] + bk4[nt][r]);
        *(bf16x4*)&Kw[bb + (size_t)hK[nt] * len * HDIM + (size_t)l * HDIM +
                      hdK[nt]] = p;
      }
    }
  } else {
    // Normal C: lane l15 = hd (within 16), reg r = token offset quad*4+r.
    float bV[4];
    int hV[4], hdV[4];
#pragma unroll
    for (int nt = 0; nt < 4; nt++) {
      int nb = wave * 64 + nt * 16 + l15;
      bV[nt] = bias[nb];
      hV[nt] = nb >> 5;
      hdV[nt] = nb & 31;
    }
    int bcur = 0;
#pragma unroll
    for (int mt = 0; mt < 4; mt++) {
      int tb = t0 + mt * 16 + quad * 4;
      if (tb >= T) continue;
      while (bcur + 1 < Bn && offs[bcur + 1] <= tb) bcur++;
      int off = offs[bcur], len = offs[bcur + 1] - off;
      size_t bb = (size_t)off * DM;
      bool span = (tb + 3 < offs[bcur + 1]) && (tb + 3 < T);
      if (span) {
        int l = tb - off;
#pragma unroll
        for (int nt = 0; nt < 4; nt++) {
          size_t idx =
              bb + (size_t)hV[nt] * len * HDIM + (size_t)hdV[nt] * len + l;
          bf16x4 p;
#pragma unroll
          for (int r = 0; r < 4; r++) p[r] = f2bf(acc[mt][nt][r] + bV[nt]);
          if ((idx & 3) == 0) {
            *(bf16x4*)&Vw[idx] = p;
          } else {
#pragma unroll
            for (int r = 0; r < 4; r++) Vw[idx + r] = p[r];
          }
        }
      } else {
        int bc2 = bcur;
#pragma unroll
        for (int r = 0; r < 4; r++) {
          int tok = tb + r;
          if (tok >= T) continue;
          while (bc2 + 1 < Bn && offs[bc2 + 1] <= tok) bc2++;
          int off2 = offs[bc2], len2 = offs[bc2 + 1] - off2;
          int l = tok - off2;
          size_t bb2 = (size_t)off2 * DM;
#pragma unroll
          for (int nt = 0; nt < 4; nt++)
            Vw[bb2 + (size_t)hV[nt] * len2 * HDIM + (size_t)hdV[nt] * len2 +
               l] = f2bf(acc[mt][nt][r] + bV[nt]);
        }
      }
    }
  }
}

// ---------------------------------------------------------------------------
// Kernel 3: flash attention per (b, h, chunk). 7 waves x 16 query rows.
// Writes unnormalized O (QPAD x 32, bf16) + per-row (m, l) fp32.
// ---------------------------------------------------------------------------
__global__ __launch_bounds__(448) void attn_kernel(
    const short* __restrict__ Qw, const short* __restrict__ Kw,
    const short* __restrict__ Vw, const int* __restrict__ offs,
    short* __restrict__ Ops, float* __restrict__ Ml, int Bn) {
  int c  = blockIdx.x % NCHUNK;
  int bh = blockIdx.x / NCHUNK;
  int h = bh % NHEAD, b = bh / NHEAD;
  int wave = threadIdx.x >> 6, lane = threadIdx.x & 63;
  int l15 = lane & 15, quad = lane >> 4;

  int off = offs[b], len = offs[b + 1] - off;
  int cl = ((len + NCHUNK * 32 - 1) / (NCHUNK * 32)) * 32;
  int kstart = c * cl;
  int kend   = min(kstart + cl, len);

  const short* Kh = Kw + (size_t)off * DM + (size_t)h * len * HDIM;
  const short* Vh = Vw + (size_t)off * DM + (size_t)h * len * HDIM;

  int row16 = wave * 16 + l15;
  bf16x8 aq = *(const bf16x8*)(
      Qw + (((size_t)b * NHEAD + h) * QPAD + row16) * HDIM + quad * 8);

  f32x4 o[2];
#pragma unroll
  for (int j = 0; j < 2; j++) o[j] = (f32x4){0.f, 0.f, 0.f, 0.f};
  float mrun[4], lrun[4];
#pragma unroll
  for (int r = 0; r < 4; r++) { mrun[r] = -1e30f; lrun[r] = 0.f; }

  __shared__ __align__(16) short plds[7][16][40];  // wave-private P transpose

  for (int kb = kstart; kb < kend; kb += 32) {
    bool valid[2];
    bf16x8 bk_[2];
#pragma unroll
    for (int nt = 0; nt < 2; nt++) {
      int key = kb + nt * 16 + l15;
      valid[nt] = key < kend;
      bk_[nt] = valid[nt]
                    ? *(const bf16x8*)(Kh + (size_t)key * HDIM + quad * 8)
                    : bzero8();
    }
    f32x4 zero = {0.f, 0.f, 0.f, 0.f};
    f32x4 s[2];
#pragma unroll
    for (int nt = 0; nt < 2; nt++)
      s[nt] = __builtin_amdgcn_mfma_f32_16x16x32_bf16(aq, bk_[nt], zero, 0, 0, 0);
#pragma unroll
    for (int r = 0; r < 4; r++) {
      float v0 = valid[0] ? s[0][r] : -1e30f;
      float v1 = valid[1] ? s[1][r] : -1e30f;
      float t = fmaxf(v0, v1);
      t = fmaxf(t, __shfl_xor(t, 1, 16));
      t = fmaxf(t, __shfl_xor(t, 2, 16));
      t = fmaxf(t, __shfl_xor(t, 4, 16));
      t = fmaxf(t, __shfl_xor(t, 8, 16));
      float mn = fmaxf(mrun[r], t);
      float al = __expf(mrun[r] - mn);
      float p0 = valid[0] ? __expf(v0 - mn) : 0.f;
      float p1 = valid[1] ? __expf(v1 - mn) : 0.f;
      float rs = p0 + p1;
      rs += __shfl_xor(rs, 1, 16);
      rs += __shfl_xor(rs, 2, 16);
      rs += __shfl_xor(rs, 4, 16);
      rs += __shfl_xor(rs, 8, 16);
      lrun[r] = al * lrun[r] + rs;
      mrun[r] = mn;
      o[0][r] *= al;
      o[1][r] *= al;
      plds[wave][quad * 4 + r][l15]      = f2bf(p0);
      plds[wave][quad * 4 + r][16 + l15] = f2bf(p1);
    }
    bf16x8 pa = *(const bf16x8*)&plds[wave][l15][quad * 8];
    bf16x8 bv_[2];
#pragma unroll
    for (int ht = 0; ht < 2; ht++) {
      int hd = ht * 16 + l15;
      int k0 = kb + quad * 8;
      const short* p = Vh + (size_t)hd * len + k0;
      if (k0 + 7 < len) {
        bv_[ht] = *(const bf16x8*)p;
      } else {
        bf16x8 v;
#pragma unroll
        for (int j = 0; j < 8; j++) v[j] = (k0 + j < len) ? p[j] : (short)0;
        bv_[ht] = v;
      }
    }
#pragma unroll
    for (int ht = 0; ht < 2; ht++)
      o[ht] = __builtin_amdgcn_mfma_f32_16x16x32_bf16(pa, bv_[ht], o[ht], 0, 0, 0);
  }

#pragma unroll
  for (int r = 0; r < 4; r++) {
    int row = wave * 16 + quad * 4 + r;
    size_t base = (((size_t)c * Bn + b) * NHEAD + h) * QPAD + row;
#pragma unroll
    for (int ht = 0; ht < 2; ht++)
      Ops[base * HDIM + ht * 16 + l15] = f2bf(o[ht][r]);
    if (l15 == 0) {
      Ml[base * 2]     = mrun[r];
      Ml[base * 2 + 1] = lrun[r];
    }
  }
}

// ---------------------------------------------------------------------------
// Kernel 4: chunk combine + out-projection + residual.
// ---------------------------------------------------------------------------
__global__ __launch_bounds__(256) void combine_kernel(
    const short* __restrict__ Ops, const float* __restrict__ Ml,
    const float* __restrict__ query, const float* __restrict__ Wo,
    const float* __restrict__ bo, float* __restrict__ out, int Bn, int NQ) {
  int bpb = (NQ + 7) / 8;
  int b  = blockIdx.x / bpb;
  int q0 = (blockIdx.x % bpb) * 8;
  __shared__ __align__(16) float ctx[8 * DM];
  int d = threadIdx.x;
  int h = d >> 5, hd = d & 31;
#pragma unroll
  for (int qi = 0; qi < 8; qi++) {
    int q = q0 + qi;
    float val = 0.f;
    if (q < NQ) {
      float mc[NCHUNK], lc[NCHUNK], M = -1e30f;
#pragma unroll
      for (int c = 0; c < NCHUNK; c++) {
        size_t base = (((size_t)c * Bn + b) * NHEAD + h) * QPAD + q;
        mc[c] = Ml[base * 2];
        lc[c] = Ml[base * 2 + 1];
        M = fmaxf(M, mc[c]);
      }
      float L = 0.f, acc = 0.f;
#pragma unroll
      for (int c = 0; c < NCHUNK; c++) {
        size_t base = (((size_t)c * Bn + b) * NHEAD + h) * QPAD + q;
        float w = __expf(mc[c] - M);
        L += lc[c] * w;
        acc += w * bf2f(Ops[base * HDIM + hd]);
      }
      val = (L > 0.f) ? acc / L : 0.f;
    }
    ctx[qi * DM + d] = val;
  }
  __syncthreads();
  const float* wrow = Wo + (size_t)d * DM;
  float acc[8];
  float bias = bo[d];
#pragma unroll
  for (int qi = 0; qi < 8; qi++) acc[qi] = bias;
  for (int k = 0; k < DM; k += 4) {
    float4 w = *(const float4*)(wrow + k);
#pragma unroll
    for (int qi = 0; qi < 8; qi++) {
      float4 x = *(const float4*)&ctx[qi * DM + k];
      acc[qi] += x.x * w.x + x.y * w.y + x.z * w.z + x.w * w.w;
    }
  }
#pragma unroll
  for (int qi = 0; qi < 8; qi++) {
    int q = q0 + qi;
    if (q < NQ)
      out[((size_t)b * NQ + q) * DM + d] =
          acc[qi] + query[((size_t)b * NQ + q) * DM + d];
  }
}

// ---------------------------------------------------------------------------
extern "C" void kernel_launch(void* const* d_in, const int* in_sizes, int n_in,
                              void* d_out, int out_size, void* d_ws,
                              size_t ws_size, hipStream_t stream) {
  const float* src   = (const float*)d_in[0];
  const float* query = (const float*)d_in[1];
  const int*   offs  = (const int*)d_in[2];
  const float* Wq = (const float*)d_in[3];
  const float* bq = (const float*)d_in[4];
  const float* Wk = (const float*)d_in[5];
  const float* bk = (const float*)d_in[6];
  const float* Wv = (const float*)d_in[7];
  const float* bv = (const float*)d_in[8];
  const float* Wo = (const float*)d_in[9];
  const float* bo = (const float*)d_in[10];
  float* out = (float*)d_out;

  int T  = in_sizes[0] / DM;        // total tokens (65536)
  int Bn = in_sizes[2] - 1;         // batch size (16)
  int NQ = in_sizes[1] / (Bn * DM); // queries per sample (100)

  // Workspace layout (~77 MB):
  char* w = (char*)d_ws;
  size_t qsz = (size_t)Bn * NHEAD * QPAD * HDIM * 2;            // 0.92 MB
  size_t ksz = (size_t)T * DM * 2;                              // 33.5 MB
  size_t osz = (size_t)NCHUNK * Bn * NHEAD * QPAD * HDIM * 2;   // 7.3 MB (bf16)
  size_t msz = (size_t)NCHUNK * Bn * NHEAD * QPAD * 2 * 4;      // 0.92 MB
  short* Qw  = (short*)w;
  short* Kw  = (short*)(w + qsz);
  short* Vw  = (short*)(w + qsz + ksz);
  short* Ops = (short*)(w + qsz + 2 * ksz);
  float* Mlp = (float*)(w + qsz + 2 * ksz + osz);
  short* Wkv = (short*)(w + qsz + 2 * ksz + osz + msz);         // 0.26 MB

  int Mtiles = (T + BM - 1) / BM;
  int groups = (Mtiles + 7) / 8;

  wconv_kernel<<<(2 * DM * DM) / (256 * 8), 256, 0, stream>>>(Wk, Wv, Wkv);
  q_proj_kernel<<<Bn * (QPAD / 8), 256, 0, stream>>>(query, Wq, bq, Qw, Bn, NQ);
  kv_gemm_kernel<<<groups * 16, 256, 0, stream>>>(
      src, Wkv, bk, bv, offs, Kw, Vw, T, Bn, Mtiles);
  attn_kernel<<<Bn * NHEAD * NCHUNK, 448, 0, stream>>>(Qw, Kw, Vw, offs, Ops,
                                                       Mlp, Bn);
  combine_kernel<<<Bn * ((NQ + 7) / 8), 256, 0, stream>>>(Ops, Mlp, query, Wo,
                                                          bo, out, Bn, NQ);
}

// Round 4
// 262.462 us; speedup vs baseline: 1.1419x; 1.0436x over previous
//
#include <hip/hip_runtime.h>
#include <hip/hip_bf16.h>
#include <math.h>

// Problem constants (fixed by the reference's weight shapes):
#define DM     256   // d_model
#define NHEAD  8
#define HDIM   32
#define QPAD   112   // padded query rows per (b,h): 7 waves x 16 rows
#define NCHUNK 8     // L-chunks per (b,h) for flash parallelism
#define BM     64    // kv_gemm M-tile (tokens)
#define BN     256   // kv_gemm N-tile (output cols): ntile 0 = K, 1 = V
#define BK     32    // kv_gemm K-step
#define ALD    264   // As row stride in shorts (256 + 8 pad)

typedef __attribute__((ext_vector_type(8))) short bf16x8;  // 8 bf16 (4 VGPRs)
typedef __attribute__((ext_vector_type(4))) short bf16x4;  // 8B packed store
typedef __attribute__((ext_vector_type(4))) float f32x4;   // 4 fp32 acc

__device__ __forceinline__ short f2bf(float f) {
  union { float f; unsigned u; } x; x.f = f;
  unsigned u = (x.u + 0x7fffu + ((x.u >> 16) & 1u)) >> 16;
  return (short)u;
}
__device__ __forceinline__ float bf2f(short s) {
  union { unsigned u; float f; } x; x.u = ((unsigned)(unsigned short)s) << 16;
  return x.f;
}
__device__ __forceinline__ bf16x8 bzero8() {
  bf16x8 v;
#pragma unroll
  for (int j = 0; j < 8; j++) v[j] = (short)0;
  return v;
}
__device__ __forceinline__ bf16x8 cvt8(const float* p) {
  float4 x0 = *(const float4*)p, x1 = *(const float4*)(p + 4);
  bf16x8 v;
  v[0] = f2bf(x0.x); v[1] = f2bf(x0.y); v[2] = f2bf(x0.z); v[3] = f2bf(x0.w);
  v[4] = f2bf(x1.x); v[5] = f2bf(x1.y); v[6] = f2bf(x1.z); v[7] = f2bf(x1.w);
  return v;
}

// ---------------------------------------------------------------------------
// Kernel 0: weight convert.  Wkv[n][k] bf16; n<256 -> Wk row n, else Wv.
// ---------------------------------------------------------------------------
__global__ __launch_bounds__(256) void wconv_kernel(
    const float* __restrict__ Wk, const float* __restrict__ Wv,
    short* __restrict__ Wkv) {
  int idx = blockIdx.x * 256 + threadIdx.x;
  int e0 = idx * 8;
  const float* p = (e0 < DM * DM) ? (Wk + e0) : (Wv + (e0 - DM * DM));
  *(bf16x8*)(Wkv + e0) = cvt8(p);
}

// ---------------------------------------------------------------------------
// Kernel 1: Q projection.  q = (query @ Wq^T + bq) * scale, bf16,
// layout Qw[b][h][row(QPAD)][hd], rows >= NQ zero-filled.
// ---------------------------------------------------------------------------
__global__ __launch_bounds__(256) void q_proj_kernel(
    const float* __restrict__ query, const float* __restrict__ Wq,
    const float* __restrict__ bq, short* __restrict__ Qw, int Bn, int NQ) {
  int b  = blockIdx.x / (QPAD / 8);
  int r0 = (blockIdx.x % (QPAD / 8)) * 8;
  __shared__ __align__(16) float ql[8 * DM];
  int tid = threadIdx.x;
  for (int i = tid; i < 8 * DM; i += 256) {
    int r = r0 + (i >> 8);
    ql[i] = (r < NQ) ? query[((size_t)b * NQ + r) * DM + (i & 255)] : 0.f;
  }
  __syncthreads();
  int d = tid;
  float bias = bq[d];
  float acc[8];
#pragma unroll
  for (int qi = 0; qi < 8; qi++) acc[qi] = bias;
  const float* wrow = Wq + (size_t)d * DM;
  for (int k = 0; k < DM; k += 4) {
    float4 w = *(const float4*)(wrow + k);
#pragma unroll
    for (int qi = 0; qi < 8; qi++) {
      float4 x = *(const float4*)&ql[qi * DM + k];
      acc[qi] += x.x * w.x + x.y * w.y + x.z * w.z + x.w * w.w;
    }
  }
  const float scale = 0.17677669529663687f;  // 1/sqrt(32)
  int h = d >> 5, hd = d & 31;
#pragma unroll
  for (int qi = 0; qi < 8; qi++) {
    int r = r0 + qi;
    float v = (r < NQ) ? acc[qi] * scale : 0.f;
    Qw[(((size_t)b * NHEAD + h) * QPAD + r) * HDIM + hd] = f2bf(v);
  }
}

// ---------------------------------------------------------------------------
// Kernel 2: KV projection GEMM, 64x256 tile, 4 waves (1x4 over N).
// Round-2 post-mortem: duration was invariant to HBM traffic -> the
// bottleneck is the per-K-step barrier+vmcnt(0) latency chain, not BW.
// Structure: stage ALL of A (64x256 bf16 = 33.8 KB) into LDS once
// (single barrier, one HBM latency for the whole block), then a K-loop with
// NO barriers and NO LDS writes: B fragments are read straight from the
// L2-resident Wkv into registers in MFMA layout (16 lanes x 512B stride,
// quads complete 64B sectors), A fragments via ds_read_b128. The compiler
// fully unrolls the 8-step loop and hoists B loads over MFMAs; waves drift
// independently (no lockstep stalls).
// K/V-paired grid kept (K and V blocks of one mtile share bid%8 -> same XCD,
// 8 IDs apart -> src re-read is an L2 hit; FETCH ~34 MB).
// K tiles use SWAPPED mfma operands (C^T: reg=hd, lane=token); V tiles
// normal orientation. Epilogue store paths unchanged.
// ---------------------------------------------------------------------------
__global__ __launch_bounds__(256) void kv_gemm_kernel(
    const float* __restrict__ src, const short* __restrict__ Wkv,
    const float* __restrict__ bk, const float* __restrict__ bv,
    const int* __restrict__ offs, short* __restrict__ Kw,
    short* __restrict__ Vw, int T, int Bn, int Mtiles) {
  int bid = blockIdx.x;
  int mtile = (bid >> 4) * 8 + (bid & 7);
  int ntile = (bid >> 3) & 1;
  if (mtile >= Mtiles) return;
  int t0 = mtile * BM;
  int n0 = ntile * BN;           // 0 => K cols, 256 => V cols
  bool isK = (ntile == 0);
  const float* bias = isK ? bk : bv;

  int tid = threadIdx.x;
  int wave = tid >> 6, lane = tid & 63;
  int l15 = lane & 15, quad = lane >> 4;

  __shared__ __align__(16) short As[BM * ALD];  // full-K A tile, bf16

  f32x4 acc[4][4];
#pragma unroll
  for (int i = 0; i < 4; i++)
#pragma unroll
    for (int j = 0; j < 4; j++) acc[i][j] = (f32x4){0.f, 0.f, 0.f, 0.f};

  // ---- prologue: stage all of A (fp32 -> bf16), one barrier total ----
  // thread -> (row = tid>>2, quarter = tid&3); 4 rounds of 16 cols each.
  {
    int arow = tid >> 2, ac4 = tid & 3;
    int atok = t0 + arow;
    if (atok >= T) atok = T - 1;
    const float* arp = src + (size_t)atok * DM;
#pragma unroll
    for (int r = 0; r < 4; r++) {
      int c0 = r * 64 + ac4 * 16;
      const float* p = arp + c0;
      bf16x8 v0 = cvt8(p);
      bf16x8 v1 = cvt8(p + 8);
      *(bf16x8*)&As[arow * ALD + c0]     = v0;
      *(bf16x8*)&As[arow * ALD + c0 + 8] = v1;
    }
  }
  __syncthreads();

  // ---- barrier-free K-loop: B from global (L2), A from LDS ----
  const short* bptr = Wkv + (size_t)(n0 + wave * 64 + l15) * DM + quad * 8;
#pragma unroll
  for (int kk = 0; kk < DM; kk += BK) {
    bf16x8 bf_[4];
#pragma unroll
    for (int nt = 0; nt < 4; nt++)
      bf_[nt] = *(const bf16x8*)(bptr + (size_t)nt * 16 * DM + kk);
    bf16x8 af[4];
#pragma unroll
    for (int mt = 0; mt < 4; mt++)
      af[mt] = *(const bf16x8*)&As[(mt * 16 + l15) * ALD + kk + quad * 8];
    if (isK) {
#pragma unroll
      for (int mt = 0; mt < 4; mt++)
#pragma unroll
        for (int nt = 0; nt < 4; nt++)
          acc[mt][nt] = __builtin_amdgcn_mfma_f32_16x16x32_bf16(
              bf_[nt], af[mt], acc[mt][nt], 0, 0, 0);  // C^T
    } else {
#pragma unroll
      for (int mt = 0; mt < 4; mt++)
#pragma unroll
        for (int nt = 0; nt < 4; nt++)
          acc[mt][nt] = __builtin_amdgcn_mfma_f32_16x16x32_bf16(
              af[mt], bf_[nt], acc[mt][nt], 0, 0, 0);
    }
  }

  if (isK) {
    // C^T: lane l15 = token (within 16), reg r = hd offset quad*4+r.
    float bk4[4][4];
    int hK[4], hdK[4];
#pragma unroll
    for (int nt = 0; nt < 4; nt++) {
      int nbq = wave * 64 + nt * 16 + quad * 4;
      float4 b4 = *(const float4*)(bias + nbq);
      bk4[nt][0] = b4.x; bk4[nt][1] = b4.y; bk4[nt][2] = b4.z; bk4[nt][3] = b4.w;
      hK[nt] = nbq >> 5;
      hdK[nt] = nbq & 31;
    }
    int bcur = 0;
#pragma unroll
    for (int mt = 0; mt < 4; mt++) {
      int tok = t0 + mt * 16 + l15;
      if (tok >= T) continue;
      while (bcur + 1 < Bn && offs[bcur + 1] <= tok) bcur++;
      int off = offs[bcur], len = offs[bcur + 1] - off;
      int l = tok - off;
      size_t bb = (size_t)off * DM;
#pragma unroll
      for (int nt = 0; nt < 4; nt++) {
        bf16x4 p;
#pragma unroll
        for (int r = 0; r < 4; r++) p[r] = f2bf(acc[mt][nt][r] + bk4[nt][r]);
        *(bf16x4*)&Kw[bb + (size_t)hK[nt] * len * HDIM + (size_t)l * HDIM +
                      hdK[nt]] = p;
      }
    }
  } else {
    // Normal C: lane l15 = hd (within 16), reg r = token offset quad*4+r.
    float bV[4];
    int hV[4], hdV[4];
#pragma unroll
    for (int nt = 0; nt < 4; nt++) {
      int nb = wave * 64 + nt * 16 + l15;
      bV[nt] = bias[nb];
      hV[nt] = nb >> 5;
      hdV[nt] = nb & 31;
    }
    int bcur = 0;
#pragma unroll
    for (int mt = 0; mt < 4; mt++) {
      int tb = t0 + mt * 16 + quad * 4;
      if (tb >= T) continue;
      while (bcur + 1 < Bn && offs[bcur + 1] <= tb) bcur++;
      int off = offs[bcur], len = offs[bcur + 1] - off;
      size_t bb = (size_t)off * DM;
      bool span = (tb + 3 < offs[bcur + 1]) && (tb + 3 < T);
      if (span) {
        int l = tb - off;
#pragma unroll
        for (int nt = 0; nt < 4; nt++) {
          size_t idx =
              bb + (size_t)hV[nt] * len * HDIM + (size_t)hdV[nt] * len + l;
          bf16x4 p;
#pragma unroll
          for (int r = 0; r < 4; r++) p[r] = f2bf(acc[mt][nt][r] + bV[nt]);
          if ((idx & 3) == 0) {
            *(bf16x4*)&Vw[idx] = p;
          } else {
#pragma unroll
            for (int r = 0; r < 4; r++) Vw[idx + r] = p[r];
          }
        }
      } else {
        int bc2 = bcur;
#pragma unroll
        for (int r = 0; r < 4; r++) {
          int tok = tb + r;
          if (tok >= T) continue;
          while (bc2 + 1 < Bn && offs[bc2 + 1] <= tok) bc2++;
          int off2 = offs[bc2], len2 = offs[bc2 + 1] - off2;
          int l = tok - off2;
          size_t bb2 = (size_t)off2 * DM;
#pragma unroll
          for (int nt = 0; nt < 4; nt++)
            Vw[bb2 + (size_t)hV[nt] * len2 * HDIM + (size_t)hdV[nt] * len2 +
               l] = f2bf(acc[mt][nt][r] + bV[nt]);
        }
      }
    }
  }
}

// ---------------------------------------------------------------------------
// Kernel 3: flash attention per (b, h, chunk). 7 waves x 16 query rows.
// Writes unnormalized O (QPAD x 32, bf16) + per-row (m, l) fp32.
// ---------------------------------------------------------------------------
__global__ __launch_bounds__(448) void attn_kernel(
    const short* __restrict__ Qw, const short* __restrict__ Kw,
    const short* __restrict__ Vw, const int* __restrict__ offs,
    short* __restrict__ Ops, float* __restrict__ Ml, int Bn) {
  int c  = blockIdx.x % NCHUNK;
  int bh = blockIdx.x / NCHUNK;
  int h = bh % NHEAD, b = bh / NHEAD;
  int wave = threadIdx.x >> 6, lane = threadIdx.x & 63;
  int l15 = lane & 15, quad = lane >> 4;

  int off = offs[b], len = offs[b + 1] - off;
  int cl = ((len + NCHUNK * 32 - 1) / (NCHUNK * 32)) * 32;
  int kstart = c * cl;
  int kend   = min(kstart + cl, len);

  const short* Kh = Kw + (size_t)off * DM + (size_t)h * len * HDIM;
  const short* Vh = Vw + (size_t)off * DM + (size_t)h * len * HDIM;

  int row16 = wave * 16 + l15;
  bf16x8 aq = *(const bf16x8*)(
      Qw + (((size_t)b * NHEAD + h) * QPAD + row16) * HDIM + quad * 8);

  f32x4 o[2];
#pragma unroll
  for (int j = 0; j < 2; j++) o[j] = (f32x4){0.f, 0.f, 0.f, 0.f};
  float mrun[4], lrun[4];
#pragma unroll
  for (int r = 0; r < 4; r++) { mrun[r] = -1e30f; lrun[r] = 0.f; }

  __shared__ __align__(16) short plds[7][16][40];  // wave-private P transpose

  for (int kb = kstart; kb < kend; kb += 32) {
    bool valid[2];
    bf16x8 bk_[2];
#pragma unroll
    for (int nt = 0; nt < 2; nt++) {
      int key = kb + nt * 16 + l15;
      valid[nt] = key < kend;
      bk_[nt] = valid[nt]
                    ? *(const bf16x8*)(Kh + (size_t)key * HDIM + quad * 8)
                    : bzero8();
    }
    f32x4 zero = {0.f, 0.f, 0.f, 0.f};
    f32x4 s[2];
#pragma unroll
    for (int nt = 0; nt < 2; nt++)
      s[nt] = __builtin_amdgcn_mfma_f32_16x16x32_bf16(aq, bk_[nt], zero, 0, 0, 0);
#pragma unroll
    for (int r = 0; r < 4; r++) {
      float v0 = valid[0] ? s[0][r] : -1e30f;
      float v1 = valid[1] ? s[1][r] : -1e30f;
      float t = fmaxf(v0, v1);
      t = fmaxf(t, __shfl_xor(t, 1, 16));
      t = fmaxf(t, __shfl_xor(t, 2, 16));
      t = fmaxf(t, __shfl_xor(t, 4, 16));
      t = fmaxf(t, __shfl_xor(t, 8, 16));
      float mn = fmaxf(mrun[r], t);
      float al = __expf(mrun[r] - mn);
      float p0 = valid[0] ? __expf(v0 - mn) : 0.f;
      float p1 = valid[1] ? __expf(v1 - mn) : 0.f;
      float rs = p0 + p1;
      rs += __shfl_xor(rs, 1, 16);
      rs += __shfl_xor(rs, 2, 16);
      rs += __shfl_xor(rs, 4, 16);
      rs += __shfl_xor(rs, 8, 16);
      lrun[r] = al * lrun[r] + rs;
      mrun[r] = mn;
      o[0][r] *= al;
      o[1][r] *= al;
      plds[wave][quad * 4 + r][l15]      = f2bf(p0);
      plds[wave][quad * 4 + r][16 + l15] = f2bf(p1);
    }
    bf16x8 pa = *(const bf16x8*)&plds[wave][l15][quad * 8];
    bf16x8 bv_[2];
#pragma unroll
    for (int ht = 0; ht < 2; ht++) {
      int hd = ht * 16 + l15;
      int k0 = kb + quad * 8;
      const short* p = Vh + (size_t)hd * len + k0;
      if (k0 + 7 < len) {
        bv_[ht] = *(const bf16x8*)p;
      } else {
        bf16x8 v;
#pragma unroll
        for (int j = 0; j < 8; j++) v[j] = (k0 + j < len) ? p[j] : (short)0;
        bv_[ht] = v;
      }
    }
#pragma unroll
    for (int ht = 0; ht < 2; ht++)
      o[ht] = __builtin_amdgcn_mfma_f32_16x16x32_bf16(pa, bv_[ht], o[ht], 0, 0, 0);
  }

#pragma unroll
  for (int r = 0; r < 4; r++) {
    int row = wave * 16 + quad * 4 + r;
    size_t base = (((size_t)c * Bn + b) * NHEAD + h) * QPAD + row;
#pragma unroll
    for (int ht = 0; ht < 2; ht++)
      Ops[base * HDIM + ht * 16 + l15] = f2bf(o[ht][r]);
    if (l15 == 0) {
      Ml[base * 2]     = mrun[r];
      Ml[base * 2 + 1] = lrun[r];
    }
  }
}

// ---------------------------------------------------------------------------
// Kernel 4: chunk combine + out-projection + residual.
// ---------------------------------------------------------------------------
__global__ __launch_bounds__(256) void combine_kernel(
    const short* __restrict__ Ops, const float* __restrict__ Ml,
    const float* __restrict__ query, const float* __restrict__ Wo,
    const float* __restrict__ bo, float* __restrict__ out, int Bn, int NQ) {
  int bpb = (NQ + 7) / 8;
  int b  = blockIdx.x / bpb;
  int q0 = (blockIdx.x % bpb) * 8;
  __shared__ __align__(16) float ctx[8 * DM];
  int d = threadIdx.x;
  int h = d >> 5, hd = d & 31;
#pragma unroll
  for (int qi = 0; qi < 8; qi++) {
    int q = q0 + qi;
    float val = 0.f;
    if (q < NQ) {
      float mc[NCHUNK], lc[NCHUNK], M = -1e30f;
#pragma unroll
      for (int c = 0; c < NCHUNK; c++) {
        size_t base = (((size_t)c * Bn + b) * NHEAD + h) * QPAD + q;
        mc[c] = Ml[base * 2];
        lc[c] = Ml[base * 2 + 1];
        M = fmaxf(M, mc[c]);
      }
      float L = 0.f, acc = 0.f;
#pragma unroll
      for (int c = 0; c < NCHUNK; c++) {
        size_t base = (((size_t)c * Bn + b) * NHEAD + h) * QPAD + q;
        float w = __expf(mc[c] - M);
        L += lc[c] * w;
        acc += w * bf2f(Ops[base * HDIM + hd]);
      }
      val = (L > 0.f) ? acc / L : 0.f;
    }
    ctx[qi * DM + d] = val;
  }
  __syncthreads();
  const float* wrow = Wo + (size_t)d * DM;
  float acc[8];
  float bias = bo[d];
#pragma unroll
  for (int qi = 0; qi < 8; qi++) acc[qi] = bias;
  for (int k = 0; k < DM; k += 4) {
    float4 w = *(const float4*)(wrow + k);
#pragma unroll
    for (int qi = 0; qi < 8; qi++) {
      float4 x = *(const float4*)&ctx[qi * DM + k];
      acc[qi] += x.x * w.x + x.y * w.y + x.z * w.z + x.w * w.w;
    }
  }
#pragma unroll
  for (int qi = 0; qi < 8; qi++) {
    int q = q0 + qi;
    if (q < NQ)
      out[((size_t)b * NQ + q) * DM + d] =
          acc[qi] + query[((size_t)b * NQ + q) * DM + d];
  }
}

// ---------------------------------------------------------------------------
extern "C" void kernel_launch(void* const* d_in, const int* in_sizes, int n_in,
                              void* d_out, int out_size, void* d_ws,
                              size_t ws_size, hipStream_t stream) {
  const float* src   = (const float*)d_in[0];
  const float* query = (const float*)d_in[1];
  const int*   offs  = (const int*)d_in[2];
  const float* Wq = (const float*)d_in[3];
  const float* bq = (const float*)d_in[4];
  const float* Wk = (const float*)d_in[5];
  const float* bk = (const float*)d_in[6];
  const float* Wv = (const float*)d_in[7];
  const float* bv = (const float*)d_in[8];
  const float* Wo = (const float*)d_in[9];
  const float* bo = (const float*)d_in[10];
  float* out = (float*)d_out;

  int T  = in_sizes[0] / DM;        // total tokens (65536)
  int Bn = in_sizes[2] - 1;         // batch size (16)
  int NQ = in_sizes[1] / (Bn * DM); // queries per sample (100)

  // Workspace layout (~77 MB):
  char* w = (char*)d_ws;
  size_t qsz = (size_t)Bn * NHEAD * QPAD * HDIM * 2;            // 0.92 MB
  size_t ksz = (size_t)T * DM * 2;                              // 33.5 MB
  size_t osz = (size_t)NCHUNK * Bn * NHEAD * QPAD * HDIM * 2;   // 7.3 MB (bf16)
  size_t msz = (size_t)NCHUNK * Bn * NHEAD * QPAD * 2 * 4;      // 0.92 MB
  short* Qw  = (short*)w;
  short* Kw  = (short*)(w + qsz);
  short* Vw  = (short*)(w + qsz + ksz);
  short* Ops = (short*)(w + qsz + 2 * ksz);
  float* Mlp = (float*)(w + qsz + 2 * ksz + osz);
  short* Wkv = (short*)(w + qsz + 2 * ksz + osz + msz);         // 0.26 MB

  int Mtiles = (T + BM - 1) / BM;
  int groups = (Mtiles + 7) / 8;

  wconv_kernel<<<(2 * DM * DM) / (256 * 8), 256, 0, stream>>>(Wk, Wv, Wkv);
  q_proj_kernel<<<Bn * (QPAD / 8), 256, 0, stream>>>(query, Wq, bq, Qw, Bn, NQ);
  kv_gemm_kernel<<<groups * 16, 256, 0, stream>>>(
      src, Wkv, bk, bv, offs, Kw, Vw, T, Bn, Mtiles);
  attn_kernel<<<Bn * NHEAD * NCHUNK, 448, 0, stream>>>(Qw, Kw, Vw, offs, Ops,
                                                       Mlp, Bn);
  combine_kernel<<<Bn * ((NQ + 7) / 8), 256, 0, stream>>>(Ops, Mlp, query, Wo,
                                                          bo, out, Bn, NQ);
}

// Round 5
// 256.440 us; speedup vs baseline: 1.1687x; 1.0235x over previous
//
#include <hip/hip_runtime.h>
#include <hip/hip_bf16.h>
#include <math.h>

// Problem constants (fixed by the reference's weight shapes):
#define DM     256   // d_model
#define NHEAD  8
#define HDIM   32
#define QPAD   112   // padded query rows per (b,h): 7 waves x 16 rows
#define NCHUNK 8     // L-chunks per (b,h) for flash parallelism
#define BM     64    // kv_gemm M-tile (tokens)
#define BN     256   // kv_gemm N-tile (output cols): ntile 0 = K, 1 = V
#define BK     32    // kv_gemm K-step
#define ALD    264   // As row stride in shorts (256 + 8 pad)
#define QR     4     // q_proj rows per block
#define CQ     4     // combine queries per block

typedef __attribute__((ext_vector_type(8))) short bf16x8;  // 8 bf16 (4 VGPRs)
typedef __attribute__((ext_vector_type(4))) short bf16x4;  // 8B packed store
typedef __attribute__((ext_vector_type(4))) float f32x4;   // 4 fp32 acc

__device__ __forceinline__ short f2bf(float f) {
  union { float f; unsigned u; } x; x.f = f;
  unsigned u = (x.u + 0x7fffu + ((x.u >> 16) & 1u)) >> 16;
  return (short)u;
}
__device__ __forceinline__ float bf2f(short s) {
  union { unsigned u; float f; } x; x.u = ((unsigned)(unsigned short)s) << 16;
  return x.f;
}
__device__ __forceinline__ bf16x8 bzero8() {
  bf16x8 v;
#pragma unroll
  for (int j = 0; j < 8; j++) v[j] = (short)0;
  return v;
}
__device__ __forceinline__ bf16x8 cvt8(const float* p) {
  float4 x0 = *(const float4*)p, x1 = *(const float4*)(p + 4);
  bf16x8 v;
  v[0] = f2bf(x0.x); v[1] = f2bf(x0.y); v[2] = f2bf(x0.z); v[3] = f2bf(x0.w);
  v[4] = f2bf(x1.x); v[5] = f2bf(x1.y); v[6] = f2bf(x1.z); v[7] = f2bf(x1.w);
  return v;
}

// ---------------------------------------------------------------------------
// Kernel 0: weight convert.  Wkv[n][k] bf16; n<256 -> Wk row n, else Wv.
// ---------------------------------------------------------------------------
__global__ __launch_bounds__(256) void wconv_kernel(
    const float* __restrict__ Wk, const float* __restrict__ Wv,
    short* __restrict__ Wkv) {
  int idx = blockIdx.x * 256 + threadIdx.x;
  int e0 = idx * 8;
  const float* p = (e0 < DM * DM) ? (Wk + e0) : (Wv + (e0 - DM * DM));
  *(bf16x8*)(Wkv + e0) = cvt8(p);
}

// ---------------------------------------------------------------------------
// Kernel 1: Q projection.  q = (query @ Wq^T + bq) * scale, bf16,
// layout Qw[b][h][row(QPAD)][hd], rows >= NQ zero-filled.
// Round-5: QR=4 rows/block (grid 224 -> 448 blocks, ~2 waves/SIMD) to cut
// the exposed per-thread latency chain of the k-loop in half.
// ---------------------------------------------------------------------------
__global__ __launch_bounds__(256) void q_proj_kernel(
    const float* __restrict__ query, const float* __restrict__ Wq,
    const float* __restrict__ bq, short* __restrict__ Qw, int Bn, int NQ) {
  int b  = blockIdx.x / (QPAD / QR);
  int r0 = (blockIdx.x % (QPAD / QR)) * QR;
  __shared__ __align__(16) float ql[QR * DM];
  int tid = threadIdx.x;
  for (int i = tid; i < QR * DM; i += 256) {
    int r = r0 + (i >> 8);
    ql[i] = (r < NQ) ? query[((size_t)b * NQ + r) * DM + (i & 255)] : 0.f;
  }
  __syncthreads();
  int d = tid;
  float bias = bq[d];
  float acc[QR];
#pragma unroll
  for (int qi = 0; qi < QR; qi++) acc[qi] = bias;
  const float* wrow = Wq + (size_t)d * DM;
  for (int k = 0; k < DM; k += 4) {
    float4 w = *(const float4*)(wrow + k);
#pragma unroll
    for (int qi = 0; qi < QR; qi++) {
      float4 x = *(const float4*)&ql[qi * DM + k];
      acc[qi] += x.x * w.x + x.y * w.y + x.z * w.z + x.w * w.w;
    }
  }
  const float scale = 0.17677669529663687f;  // 1/sqrt(32)
  int h = d >> 5, hd = d & 31;
#pragma unroll
  for (int qi = 0; qi < QR; qi++) {
    int r = r0 + qi;
    float v = (r < NQ) ? acc[qi] * scale : 0.f;
    Qw[(((size_t)b * NHEAD + h) * QPAD + r) * HDIM + hd] = f2bf(v);
  }
}

// ---------------------------------------------------------------------------
// Kernel 2: KV projection GEMM, 64x256 tile, 4 waves (1x4 over N).
// Best measured config (70 us): stage ALL of A (64x256 bf16 = 33.8 KB) into
// LDS once, then a barrier-free K-loop: B fragments straight from the
// L2-resident Wkv into registers in MFMA layout, A via ds_read_b128.
// K/V-paired grid (K and V blocks of one mtile share bid%8 -> same XCD,
// 8 IDs apart -> src re-read is an L2 hit; FETCH ~34 MB).
// K tiles use SWAPPED mfma operands (C^T); V tiles normal orientation.
// ---------------------------------------------------------------------------
__global__ __launch_bounds__(256) void kv_gemm_kernel(
    const float* __restrict__ src, const short* __restrict__ Wkv,
    const float* __restrict__ bk, const float* __restrict__ bv,
    const int* __restrict__ offs, short* __restrict__ Kw,
    short* __restrict__ Vw, int T, int Bn, int Mtiles) {
  int bid = blockIdx.x;
  int mtile = (bid >> 4) * 8 + (bid & 7);
  int ntile = (bid >> 3) & 1;
  if (mtile >= Mtiles) return;
  int t0 = mtile * BM;
  int n0 = ntile * BN;           // 0 => K cols, 256 => V cols
  bool isK = (ntile == 0);
  const float* bias = isK ? bk : bv;

  int tid = threadIdx.x;
  int wave = tid >> 6, lane = tid & 63;
  int l15 = lane & 15, quad = lane >> 4;

  __shared__ __align__(16) short As[BM * ALD];  // full-K A tile, bf16

  f32x4 acc[4][4];
#pragma unroll
  for (int i = 0; i < 4; i++)
#pragma unroll
    for (int j = 0; j < 4; j++) acc[i][j] = (f32x4){0.f, 0.f, 0.f, 0.f};

  // ---- prologue: stage all of A (fp32 -> bf16), one barrier total ----
  {
    int arow = tid >> 2, ac4 = tid & 3;
    int atok = t0 + arow;
    if (atok >= T) atok = T - 1;
    const float* arp = src + (size_t)atok * DM;
#pragma unroll
    for (int r = 0; r < 4; r++) {
      int c0 = r * 64 + ac4 * 16;
      const float* p = arp + c0;
      bf16x8 v0 = cvt8(p);
      bf16x8 v1 = cvt8(p + 8);
      *(bf16x8*)&As[arow * ALD + c0]     = v0;
      *(bf16x8*)&As[arow * ALD + c0 + 8] = v1;
    }
  }
  __syncthreads();

  // ---- barrier-free K-loop: B from global (L2), A from LDS ----
  const short* bptr = Wkv + (size_t)(n0 + wave * 64 + l15) * DM + quad * 8;
#pragma unroll
  for (int kk = 0; kk < DM; kk += BK) {
    bf16x8 bf_[4];
#pragma unroll
    for (int nt = 0; nt < 4; nt++)
      bf_[nt] = *(const bf16x8*)(bptr + (size_t)nt * 16 * DM + kk);
    bf16x8 af[4];
#pragma unroll
    for (int mt = 0; mt < 4; mt++)
      af[mt] = *(const bf16x8*)&As[(mt * 16 + l15) * ALD + kk + quad * 8];
    if (isK) {
#pragma unroll
      for (int mt = 0; mt < 4; mt++)
#pragma unroll
        for (int nt = 0; nt < 4; nt++)
          acc[mt][nt] = __builtin_amdgcn_mfma_f32_16x16x32_bf16(
              bf_[nt], af[mt], acc[mt][nt], 0, 0, 0);  // C^T
    } else {
#pragma unroll
      for (int mt = 0; mt < 4; mt++)
#pragma unroll
        for (int nt = 0; nt < 4; nt++)
          acc[mt][nt] = __builtin_amdgcn_mfma_f32_16x16x32_bf16(
              af[mt], bf_[nt], acc[mt][nt], 0, 0, 0);
    }
  }

  if (isK) {
    // C^T: lane l15 = token (within 16), reg r = hd offset quad*4+r.
    float bk4[4][4];
    int hK[4], hdK[4];
#pragma unroll
    for (int nt = 0; nt < 4; nt++) {
      int nbq = wave * 64 + nt * 16 + quad * 4;
      float4 b4 = *(const float4*)(bias + nbq);
      bk4[nt][0] = b4.x; bk4[nt][1] = b4.y; bk4[nt][2] = b4.z; bk4[nt][3] = b4.w;
      hK[nt] = nbq >> 5;
      hdK[nt] = nbq & 31;
    }
    int bcur = 0;
#pragma unroll
    for (int mt = 0; mt < 4; mt++) {
      int tok = t0 + mt * 16 + l15;
      if (tok >= T) continue;
      while (bcur + 1 < Bn && offs[bcur + 1] <= tok) bcur++;
      int off = offs[bcur], len = offs[bcur + 1] - off;
      int l = tok - off;
      size_t bb = (size_t)off * DM;
#pragma unroll
      for (int nt = 0; nt < 4; nt++) {
        bf16x4 p;
#pragma unroll
        for (int r = 0; r < 4; r++) p[r] = f2bf(acc[mt][nt][r] + bk4[nt][r]);
        *(bf16x4*)&Kw[bb + (size_t)hK[nt] * len * HDIM + (size_t)l * HDIM +
                      hdK[nt]] = p;
      }
    }
  } else {
    // Normal C: lane l15 = hd (within 16), reg r = token offset quad*4+r.
    float bV[4];
    int hV[4], hdV[4];
#pragma unroll
    for (int nt = 0; nt < 4; nt++) {
      int nb = wave * 64 + nt * 16 + l15;
      bV[nt] = bias[nb];
      hV[nt] = nb >> 5;
      hdV[nt] = nb & 31;
    }
    int bcur = 0;
#pragma unroll
    for (int mt = 0; mt < 4; mt++) {
      int tb = t0 + mt * 16 + quad * 4;
      if (tb >= T) continue;
      while (bcur + 1 < Bn && offs[bcur + 1] <= tb) bcur++;
      int off = offs[bcur], len = offs[bcur + 1] - off;
      size_t bb = (size_t)off * DM;
      bool span = (tb + 3 < offs[bcur + 1]) && (tb + 3 < T);
      if (span) {
        int l = tb - off;
#pragma unroll
        for (int nt = 0; nt < 4; nt++) {
          size_t idx =
              bb + (size_t)hV[nt] * len * HDIM + (size_t)hdV[nt] * len + l;
          bf16x4 p;
#pragma unroll
          for (int r = 0; r < 4; r++) p[r] = f2bf(acc[mt][nt][r] + bV[nt]);
          if ((idx & 3) == 0) {
            *(bf16x4*)&Vw[idx] = p;
          } else {
#pragma unroll
            for (int r = 0; r < 4; r++) Vw[idx + r] = p[r];
          }
        }
      } else {
        int bc2 = bcur;
#pragma unroll
        for (int r = 0; r < 4; r++) {
          int tok = tb + r;
          if (tok >= T) continue;
          while (bc2 + 1 < Bn && offs[bc2 + 1] <= tok) bc2++;
          int off2 = offs[bc2], len2 = offs[bc2 + 1] - off2;
          int l = tok - off2;
          size_t bb2 = (size_t)off2 * DM;
#pragma unroll
          for (int nt = 0; nt < 4; nt++)
            Vw[bb2 + (size_t)hV[nt] * len2 * HDIM + (size_t)hdV[nt] * len2 +
               l] = f2bf(acc[mt][nt][r] + bV[nt]);
        }
      }
    }
  }
}

// ---------------------------------------------------------------------------
// Kernel 3: flash attention per (b, h, chunk). 7 waves x 16 query rows.
// Writes unnormalized O (QPAD x 32, bf16) + per-row (m, l) fp32.
// ---------------------------------------------------------------------------
__global__ __launch_bounds__(448) void attn_kernel(
    const short* __restrict__ Qw, const short* __restrict__ Kw,
    const short* __restrict__ Vw, const int* __restrict__ offs,
    short* __restrict__ Ops, float* __restrict__ Ml, int Bn) {
  int c  = blockIdx.x % NCHUNK;
  int bh = blockIdx.x / NCHUNK;
  int h = bh % NHEAD, b = bh / NHEAD;
  int wave = threadIdx.x >> 6, lane = threadIdx.x & 63;
  int l15 = lane & 15, quad = lane >> 4;

  int off = offs[b], len = offs[b + 1] - off;
  int cl = ((len + NCHUNK * 32 - 1) / (NCHUNK * 32)) * 32;
  int kstart = c * cl;
  int kend   = min(kstart + cl, len);

  const short* Kh = Kw + (size_t)off * DM + (size_t)h * len * HDIM;
  const short* Vh = Vw + (size_t)off * DM + (size_t)h * len * HDIM;

  int row16 = wave * 16 + l15;
  bf16x8 aq = *(const bf16x8*)(
      Qw + (((size_t)b * NHEAD + h) * QPAD + row16) * HDIM + quad * 8);

  f32x4 o[2];
#pragma unroll
  for (int j = 0; j < 2; j++) o[j] = (f32x4){0.f, 0.f, 0.f, 0.f};
  float mrun[4], lrun[4];
#pragma unroll
  for (int r = 0; r < 4; r++) { mrun[r] = -1e30f; lrun[r] = 0.f; }

  __shared__ __align__(16) short plds[7][16][40];  // wave-private P transpose

  for (int kb = kstart; kb < kend; kb += 32) {
    bool valid[2];
    bf16x8 bk_[2];
#pragma unroll
    for (int nt = 0; nt < 2; nt++) {
      int key = kb + nt * 16 + l15;
      valid[nt] = key < kend;
      bk_[nt] = valid[nt]
                    ? *(const bf16x8*)(Kh + (size_t)key * HDIM + quad * 8)
                    : bzero8();
    }
    f32x4 zero = {0.f, 0.f, 0.f, 0.f};
    f32x4 s[2];
#pragma unroll
    for (int nt = 0; nt < 2; nt++)
      s[nt] = __builtin_amdgcn_mfma_f32_16x16x32_bf16(aq, bk_[nt], zero, 0, 0, 0);
#pragma unroll
    for (int r = 0; r < 4; r++) {
      float v0 = valid[0] ? s[0][r] : -1e30f;
      float v1 = valid[1] ? s[1][r] : -1e30f;
      float t = fmaxf(v0, v1);
      t = fmaxf(t, __shfl_xor(t, 1, 16));
      t = fmaxf(t, __shfl_xor(t, 2, 16));
      t = fmaxf(t, __shfl_xor(t, 4, 16));
      t = fmaxf(t, __shfl_xor(t, 8, 16));
      float mn = fmaxf(mrun[r], t);
      float al = __expf(mrun[r] - mn);
      float p0 = valid[0] ? __expf(v0 - mn) : 0.f;
      float p1 = valid[1] ? __expf(v1 - mn) : 0.f;
      float rs = p0 + p1;
      rs += __shfl_xor(rs, 1, 16);
      rs += __shfl_xor(rs, 2, 16);
      rs += __shfl_xor(rs, 4, 16);
      rs += __shfl_xor(rs, 8, 16);
      lrun[r] = al * lrun[r] + rs;
      mrun[r] = mn;
      o[0][r] *= al;
      o[1][r] *= al;
      plds[wave][quad * 4 + r][l15]      = f2bf(p0);
      plds[wave][quad * 4 + r][16 + l15] = f2bf(p1);
    }
    bf16x8 pa = *(const bf16x8*)&plds[wave][l15][quad * 8];
    bf16x8 bv_[2];
#pragma unroll
    for (int ht = 0; ht < 2; ht++) {
      int hd = ht * 16 + l15;
      int k0 = kb + quad * 8;
      const short* p = Vh + (size_t)hd * len + k0;
      if (k0 + 7 < len) {
        bv_[ht] = *(const bf16x8*)p;
      } else {
        bf16x8 v;
#pragma unroll
        for (int j = 0; j < 8; j++) v[j] = (k0 + j < len) ? p[j] : (short)0;
        bv_[ht] = v;
      }
    }
#pragma unroll
    for (int ht = 0; ht < 2; ht++)
      o[ht] = __builtin_amdgcn_mfma_f32_16x16x32_bf16(pa, bv_[ht], o[ht], 0, 0, 0);
  }

#pragma unroll
  for (int r = 0; r < 4; r++) {
    int row = wave * 16 + quad * 4 + r;
    size_t base = (((size_t)c * Bn + b) * NHEAD + h) * QPAD + row;
#pragma unroll
    for (int ht = 0; ht < 2; ht++)
      Ops[base * HDIM + ht * 16 + l15] = f2bf(o[ht][r]);
    if (l15 == 0) {
      Ml[base * 2]     = mrun[r];
      Ml[base * 2 + 1] = lrun[r];
    }
  }
}

// ---------------------------------------------------------------------------
// Kernel 4: chunk combine + out-projection + residual.
// Round-5: CQ=4 queries/block (grid 208 -> 400) and LDS-staged, VECTORIZED
// Ops/Ml loads (bf16x8 / float2-equivalent) replacing 64 scalar 2B global
// reads + 128 scalar Ml reads per thread.
// ---------------------------------------------------------------------------
__global__ __launch_bounds__(256) void combine_kernel(
    const short* __restrict__ Ops, const float* __restrict__ Ml,
    const float* __restrict__ query, const float* __restrict__ Wo,
    const float* __restrict__ bo, float* __restrict__ out, int Bn, int NQ) {
  int bpb = (NQ + CQ - 1) / CQ;
  int b  = blockIdx.x / bpb;
  int q0 = (blockIdx.x % bpb) * CQ;
  int tid = threadIdx.x;

  __shared__ __align__(16) short opsl[CQ][NCHUNK][DM];  // 16 KB
  __shared__ float mll[NCHUNK][NHEAD][CQ][2];           // 2 KB
  __shared__ __align__(16) float ctx[CQ * DM];          // 4 KB

  // stage Ops: CQ*NCHUNK*(DM/8) = 1024 vector loads, 4 per thread
  for (int t = tid; t < CQ * NCHUNK * (DM / 8); t += 256) {
    int q   = t / (NCHUNK * 32);
    int rem = t % (NCHUNK * 32);
    int c   = rem / 32;
    int v   = rem % 32;           // 8-elem chunk within 256 = h*32+hd0
    int h   = v >> 2;
    int hd0 = (v & 3) * 8;
    int qq = q0 + q;
    if (qq >= NQ) qq = NQ - 1;
    size_t base = (((size_t)c * Bn + b) * NHEAD + h) * QPAD + qq;
    *(bf16x8*)&opsl[q][c][v * 8] = *(const bf16x8*)&Ops[base * HDIM + hd0];
  }
  // stage Ml: CQ*NCHUNK*NHEAD = 256 (m,l) pairs, 1 per thread
  for (int t = tid; t < CQ * NCHUNK * NHEAD; t += 256) {
    int q   = t / (NCHUNK * NHEAD);
    int rem = t % (NCHUNK * NHEAD);
    int c   = rem / NHEAD;
    int h   = rem % NHEAD;
    int qq = q0 + q;
    if (qq >= NQ) qq = NQ - 1;
    size_t base = (((size_t)c * Bn + b) * NHEAD + h) * QPAD + qq;
    mll[c][h][q][0] = Ml[base * 2];
    mll[c][h][q][1] = Ml[base * 2 + 1];
  }
  __syncthreads();

  int d = tid, h = d >> 5;
#pragma unroll
  for (int qi = 0; qi < CQ; qi++) {
    float M = -1e30f;
#pragma unroll
    for (int c = 0; c < NCHUNK; c++) M = fmaxf(M, mll[c][h][qi][0]);
    float L = 0.f, acc = 0.f;
#pragma unroll
    for (int c = 0; c < NCHUNK; c++) {
      float w = __expf(mll[c][h][qi][0] - M);
      L += mll[c][h][qi][1] * w;
      acc += w * bf2f(opsl[qi][c][d]);
    }
    ctx[qi * DM + d] = (L > 0.f) ? acc / L : 0.f;
  }
  __syncthreads();

  const float* wrow = Wo + (size_t)d * DM;
  float acc[CQ];
  float bias = bo[d];
#pragma unroll
  for (int qi = 0; qi < CQ; qi++) acc[qi] = bias;
  for (int k = 0; k < DM; k += 4) {
    float4 w = *(const float4*)(wrow + k);
#pragma unroll
    for (int qi = 0; qi < CQ; qi++) {
      float4 x = *(const float4*)&ctx[qi * DM + k];
      acc[qi] += x.x * w.x + x.y * w.y + x.z * w.z + x.w * w.w;
    }
  }
#pragma unroll
  for (int qi = 0; qi < CQ; qi++) {
    int q = q0 + qi;
    if (q < NQ)
      out[((size_t)b * NQ + q) * DM + d] =
          acc[qi] + query[((size_t)b * NQ + q) * DM + d];
  }
}

// ---------------------------------------------------------------------------
extern "C" void kernel_launch(void* const* d_in, const int* in_sizes, int n_in,
                              void* d_out, int out_size, void* d_ws,
                              size_t ws_size, hipStream_t stream) {
  const float* src   = (const float*)d_in[0];
  const float* query = (const float*)d_in[1];
  const int*   offs  = (const int*)d_in[2];
  const float* Wq = (const float*)d_in[3];
  const float* bq = (const float*)d_in[4];
  const float* Wk = (const float*)d_in[5];
  const float* bk = (const float*)d_in[6];
  const float* Wv = (const float*)d_in[7];
  const float* bv = (const float*)d_in[8];
  const float* Wo = (const float*)d_in[9];
  const float* bo = (const float*)d_in[10];
  float* out = (float*)d_out;

  int T  = in_sizes[0] / DM;        // total tokens (65536)
  int Bn = in_sizes[2] - 1;         // batch size (16)
  int NQ = in_sizes[1] / (Bn * DM); // queries per sample (100)

  // Workspace layout (~77 MB):
  char* w = (char*)d_ws;
  size_t qsz = (size_t)Bn * NHEAD * QPAD * HDIM * 2;            // 0.92 MB
  size_t ksz = (size_t)T * DM * 2;                              // 33.5 MB
  size_t osz = (size_t)NCHUNK * Bn * NHEAD * QPAD * HDIM * 2;   // 7.3 MB (bf16)
  size_t msz = (size_t)NCHUNK * Bn * NHEAD * QPAD * 2 * 4;      // 0.92 MB
  short* Qw  = (short*)w;
  short* Kw  = (short*)(w + qsz);
  short* Vw  = (short*)(w + qsz + ksz);
  short* Ops = (short*)(w + qsz + 2 * ksz);
  float* Mlp = (float*)(w + qsz + 2 * ksz + osz);
  short* Wkv = (short*)(w + qsz + 2 * ksz + osz + msz);         // 0.26 MB

  int Mtiles = (T + BM - 1) / BM;
  int groups = (Mtiles + 7) / 8;

  wconv_kernel<<<(2 * DM * DM) / (256 * 8), 256, 0, stream>>>(Wk, Wv, Wkv);
  q_proj_kernel<<<Bn * (QPAD / QR), 256, 0, stream>>>(query, Wq, bq, Qw, Bn,
                                                      NQ);
  kv_gemm_kernel<<<groups * 16, 256, 0, stream>>>(
      src, Wkv, bk, bv, offs, Kw, Vw, T, Bn, Mtiles);
  attn_kernel<<<Bn * NHEAD * NCHUNK, 448, 0, stream>>>(Qw, Kw, Vw, offs, Ops,
                                                       Mlp, Bn);
  combine_kernel<<<Bn * ((NQ + CQ - 1) / CQ), 256, 0, stream>>>(
      Ops, Mlp, query, Wo, bo, out, Bn, NQ);
}